// Round 11
// baseline (436.288 us; speedup 1.0000x reference)
//
#include <hip/hip_runtime.h>
#include <hip/hip_bf16.h>

#define HH    128
#define NHEAD 8
#define HDIM  16
#define EDIM  32
#define FFDIM 512
#define BM    16     // node rows per block (qkv + tail)
#define CHUNK 16     // edges per chunk in edge_kernel

// ---------------------------------------------------------------------------
// K1: q,k,v projections, tiled: BM=16 rows/block, 512 threads.
// Also zeroes cnt/cursor for the CSR build (ws is poisoned each call).
// ---------------------------------------------------------------------------
__global__ __launch_bounds__(512)
void qkv_kernel(const float* __restrict__ x,
                const float* __restrict__ Wq, const float* __restrict__ bq,
                const float* __restrict__ Wk, const float* __restrict__ bk,
                const float* __restrict__ Wv, const float* __restrict__ bv,
                float* __restrict__ q, float* __restrict__ k, float* __restrict__ v,
                int* __restrict__ cnt, int* __restrict__ cursor)
{
    const int row0 = blockIdx.x * BM;
    const int t  = threadIdx.x;
    const int rg = t >> 7;
    const int c  = t & 127;
    __shared__ float xs[BM * HH];

    if (t < BM)                cnt[row0 + t] = 0;
    else if (t < 2 * BM)       cursor[row0 + (t - BM)] = 0;
    // stage x tile (16 rows x 128) — 4 floats per thread, coalesced
    *(float4*)&xs[t * 4] = *(const float4*)&x[(size_t)row0 * HH + t * 4];
    __syncthreads();

    float aq[4] = {0.f, 0.f, 0.f, 0.f};
    float ak[4] = {0.f, 0.f, 0.f, 0.f};
    float av[4] = {0.f, 0.f, 0.f, 0.f};
    for (int i0 = 0; i0 < HH; i0 += 4) {
        float4 xr[4];
        #pragma unroll
        for (int r = 0; r < 4; ++r)
            xr[r] = *(const float4*)&xs[(4 * rg + r) * HH + i0];   // wave-broadcast
        #pragma unroll
        for (int u = 0; u < 4; ++u) {
            float wq = Wq[(i0 + u) * HH + c];
            float wk = Wk[(i0 + u) * HH + c];
            float wv = Wv[(i0 + u) * HH + c];
            #pragma unroll
            for (int r = 0; r < 4; ++r) {
                float xv = ((const float*)&xr[r])[u];
                aq[r] += xv * wq;  ak[r] += xv * wk;  av[r] += xv * wv;
            }
        }
    }
    float bqv = bq[c], bkv = bk[c], bvv = bv[c];
    #pragma unroll
    for (int r = 0; r < 4; ++r) {
        size_t o = (size_t)(row0 + 4 * rg + r) * HH + c;
        q[o] = aq[r] + bqv;
        k[o] = ak[r] + bkv;
        v[o] = av[r] + bvv;
    }
}

// ---------------------------------------------------------------------------
// K2: degree histogram over dst
// ---------------------------------------------------------------------------
__global__ void hist_kernel(const int* __restrict__ ei, int E, int* __restrict__ cnt)
{
    int e = blockIdx.x * 256 + threadIdx.x;
    if (e < E) atomicAdd(&cnt[ei[E + e]], 1);
}

// ---------------------------------------------------------------------------
// K3: exclusive prefix sum of cnt[0..n) -> rowptr[0..n]  (single block)
// ---------------------------------------------------------------------------
#define SCAN_T 1024
__global__ __launch_bounds__(SCAN_T)
void scan_kernel(const int* __restrict__ cnt, int n, int* __restrict__ rowptr)
{
    __shared__ int part[SCAN_T];
    const int t = threadIdx.x;
    const int per = (n + SCAN_T - 1) / SCAN_T;
    const int beg = t * per;
    const int end = min(beg + per, n);
    int sum = 0;
    for (int i = beg; i < end; ++i) sum += cnt[i];
    part[t] = sum;
    __syncthreads();
    // Hillis-Steele inclusive scan
    for (int off = 1; off < SCAN_T; off <<= 1) {
        int vv = (t >= off) ? part[t - off] : 0;
        __syncthreads();
        part[t] += vv;
        __syncthreads();
    }
    int base = (t == 0) ? 0 : part[t - 1];
    for (int i = beg; i < end; ++i) { rowptr[i] = base; base += cnt[i]; }
    if (t == SCAN_T - 1) rowptr[n] = base;
}

// ---------------------------------------------------------------------------
// K4: scatter edges into CSR slots; compute edge bias (ea@We+be) into
//     csr_eb (CSR-ordered so the edge kernel reads it contiguously).
// ---------------------------------------------------------------------------
__global__ __launch_bounds__(256)
void scatter_kernel(const int* __restrict__ ei, int E,
                    const float* __restrict__ ea,
                    const float* __restrict__ We, const float* __restrict__ be,
                    const int* __restrict__ rowptr, int* __restrict__ cursor,
                    int* __restrict__ csr_src, float* __restrict__ csr_eb)
{
    __shared__ float wsh[EDIM * NHEAD];
    __shared__ float bsh[NHEAD];
    const int t = threadIdx.x;
    if (t < EDIM * NHEAD) wsh[t] = We[t];
    if (t < NHEAD) bsh[t] = be[t];
    __syncthreads();
    int e = blockIdx.x * 256 + t;
    if (e >= E) return;
    int src = ei[e], dst = ei[E + e];
    int slot = rowptr[dst] + atomicAdd(&cursor[dst], 1);
    csr_src[slot] = src;
    float eb[NHEAD];
    #pragma unroll
    for (int h = 0; h < NHEAD; ++h) eb[h] = bsh[h];
    const float* eap = ea + (size_t)e * EDIM;
    #pragma unroll
    for (int j0 = 0; j0 < EDIM; j0 += 4) {
        float4 a = *(const float4*)&eap[j0];
        #pragma unroll
        for (int h = 0; h < NHEAD; ++h) {
            eb[h] += a.x * wsh[(j0    ) * NHEAD + h]
                   + a.y * wsh[(j0 + 1) * NHEAD + h]
                   + a.z * wsh[(j0 + 2) * NHEAD + h]
                   + a.w * wsh[(j0 + 3) * NHEAD + h];
        }
    }
    #pragma unroll
    for (int h = 0; h < NHEAD; ++h) csr_eb[(size_t)slot * NHEAD + h] = eb[h];
}

// ---------------------------------------------------------------------------
// K5: fused edge phase — per dst node: scores + online softmax + weighted
// aggregation. One block of 128 threads per node. No atomics.
// ---------------------------------------------------------------------------
__global__ __launch_bounds__(128)
void edge_kernel(const float* __restrict__ q, const float* __restrict__ k,
                 const float* __restrict__ v,
                 const int* __restrict__ rowptr,
                 const int* __restrict__ csr_src, const float* __restrict__ csr_eb,
                 float* __restrict__ agg)
{
    const int node = blockIdx.x;
    const int t = threadIdx.x;
    const int c = t >> 3, h = t & 7;
    const int f = t, fh = t >> 4;
    __shared__ float ks[HH];
    __shared__ float sraw[CHUNK][NHEAD];
    __shared__ float p[CHUNK][NHEAD];
    __shared__ int   ssrc[CHUNK];
    __shared__ float m[NHEAD], dn[NHEAD], fac[NHEAD];

    ks[t] = k[(size_t)node * HH + t];
    if (t < NHEAD) { m[t] = -3.0e38f; dn[t] = 0.f; }
    const int beg = rowptr[node], end = rowptr[node + 1];
    float acc = 0.f;
    __syncthreads();

    for (int b0 = beg; b0 < end; b0 += CHUNK) {
        const int C = min(CHUNK, end - b0);
        float sc = -3.0e38f;
        if (c < C) {
            int src = csr_src[b0 + c];          // 8 lanes same addr -> broadcast
            if (h == 0) ssrc[c] = src;
            const float* qp = q + (size_t)src * HH + h * HDIM;
            float d0 = 0.f;
            #pragma unroll
            for (int d = 0; d < HDIM; d += 4) {
                float4 qv = *(const float4*)&qp[d];
                d0 += qv.x * ks[h * HDIM + d]     + qv.y * ks[h * HDIM + d + 1]
                    + qv.z * ks[h * HDIM + d + 2] + qv.w * ks[h * HDIM + d + 3];
            }
            sc = d0 * 0.25f + csr_eb[(size_t)(b0 + c) * NHEAD + h];  // contiguous
        }
        sraw[c][h] = sc;
        __syncthreads();
        if (t < NHEAD) {
            float mo = m[t], mc = -3.0e38f;
            #pragma unroll 4
            for (int cc = 0; cc < CHUNK; ++cc) mc = fmaxf(mc, sraw[cc][t]);
            float mn = fmaxf(mo, mc);
            float fa = __expf(mo - mn);
            float s = 0.f;
            #pragma unroll 4
            for (int cc = 0; cc < CHUNK; ++cc) {
                float pe = __expf(sraw[cc][t] - mn);
                p[cc][t] = pe;  s += pe;
            }
            dn[t] = dn[t] * fa + s;
            m[t] = mn;  fac[t] = fa;
        }
        __syncthreads();
        acc *= fac[fh];
        for (int cc = 0; cc < C; ++cc)
            acc += p[cc][fh] * v[(size_t)ssrc[cc] * HH + f];   // 512B coalesced
        __syncthreads();   // protect LDS for next chunk
    }
    agg[(size_t)node * HH + f] = acc / (dn[fh] + 1e-8f);
}

// ---------------------------------------------------------------------------
// K6 (fused tail): out0 = agg@Wo+bo; x1 = LN1(x+out0);
//                  h = gelu(x1@W1+b1); out = LN2(x1 + h@W2+b2)
// BM=16 rows, 512 threads: r=t>>5 (row), g=t&31 (4-col group).
// ALL weight loads are float4/coalesced; LN reductions are pure shfl_xor
// within 32-lane groups (lanes of one row are contiguous in the wave).
// FF-column ownership 4g+128*cc4 -> conflict-free hs writes + contiguous
// W1 loads. 4 barriers total.
// ---------------------------------------------------------------------------
__global__ __launch_bounds__(512)
void tail_kernel(const float* __restrict__ x, const float* __restrict__ agg,
                 const float* __restrict__ Wo, const float* __restrict__ bo,
                 const float* __restrict__ l1g, const float* __restrict__ l1b,
                 const float* __restrict__ W1, const float* __restrict__ b1,
                 const float* __restrict__ W2, const float* __restrict__ b2,
                 const float* __restrict__ l2g, const float* __restrict__ l2b,
                 float* __restrict__ out)
{
    const int row0 = blockIdx.x * BM;
    const int t = threadIdx.x;
    const int r = t >> 5;          // 0..15
    const int g = t & 31;          // cols 4g..4g+3
    const int row = row0 + r;

    __shared__ float xs[BM * HH];       // agg tile, then x1 tile (8KB)
    __shared__ float hs[BM * FFDIM];    // gelu(h) tile (32KB)

    // stage agg tile: 4 floats/thread, coalesced
    *(float4*)&xs[t * 4] = *(const float4*)&agg[(size_t)row0 * HH + t * 4];
    __syncthreads();

    // ---- oproj: y = (agg @ Wo)[row, 4g..4g+3] ----
    float4 y = make_float4(0.f, 0.f, 0.f, 0.f);
    for (int i0 = 0; i0 < HH; i0 += 4) {
        float4 av = *(const float4*)&xs[r * HH + i0];          // LDS broadcast
        #pragma unroll
        for (int u = 0; u < 4; ++u) {
            float4 w = *(const float4*)&Wo[(size_t)(i0 + u) * HH + 4 * g];
            float a = ((const float*)&av)[u];
            y.x += a * w.x;  y.y += a * w.y;  y.z += a * w.z;  y.w += a * w.w;
        }
    }
    {
        float4 bov = *(const float4*)&bo[4 * g];
        float4 xv  = *(const float4*)&x[(size_t)row * HH + 4 * g];   // residual
        y.x += bov.x + xv.x;  y.y += bov.y + xv.y;
        y.z += bov.z + xv.z;  y.w += bov.w + xv.w;
    }

    // ---- LN1: reduce across 32 lanes (one row) via shfl_xor ----
    float s  = y.x + y.y + y.z + y.w;
    float s2 = y.x * y.x + y.y * y.y + y.z * y.z + y.w * y.w;
    #pragma unroll
    for (int mask = 16; mask > 0; mask >>= 1) {
        s  += __shfl_xor(s,  mask);
        s2 += __shfl_xor(s2, mask);
    }
    float mean = s * (1.0f / HH);
    float var  = s2 * (1.0f / HH) - mean * mean;
    float rstd = rsqrtf(var + 1e-5f);
    float4 x1v;
    {
        float4 gg = *(const float4*)&l1g[4 * g];
        float4 bb = *(const float4*)&l1b[4 * g];
        x1v.x = (y.x - mean) * rstd * gg.x + bb.x;
        x1v.y = (y.y - mean) * rstd * gg.y + bb.y;
        x1v.z = (y.z - mean) * rstd * gg.z + bb.z;
        x1v.w = (y.w - mean) * rstd * gg.w + bb.w;
    }
    __syncthreads();                       // all xs(agg) reads done
    *(float4*)&xs[r * HH + 4 * g] = x1v;   // conflict-free (contiguous per row)
    __syncthreads();

    // ---- FFN GEMM1: h for FF cols {4g+128*cc4 + e} ----
    float4 h4[4];
    #pragma unroll
    for (int c4 = 0; c4 < 4; ++c4) h4[c4] = make_float4(0.f, 0.f, 0.f, 0.f);
    for (int i0 = 0; i0 < HH; i0 += 4) {
        float4 xv = *(const float4*)&xs[r * HH + i0];          // LDS broadcast
        #pragma unroll
        for (int u = 0; u < 4; ++u) {
            const float* wrow = &W1[(size_t)(i0 + u) * FFDIM + 4 * g];
            float xu = ((const float*)&xv)[u];
            #pragma unroll
            for (int c4 = 0; c4 < 4; ++c4) {
                float4 w = *(const float4*)&wrow[128 * c4];    // 512B/instr
                h4[c4].x += xu * w.x;  h4[c4].y += xu * w.y;
                h4[c4].z += xu * w.z;  h4[c4].w += xu * w.w;
            }
        }
    }
    #pragma unroll
    for (int c4 = 0; c4 < 4; ++c4) {
        float4 bv = *(const float4*)&b1[4 * g + 128 * c4];
        float a0 = h4[c4].x + bv.x, a1 = h4[c4].y + bv.y;
        float a2 = h4[c4].z + bv.z, a3 = h4[c4].w + bv.w;
        float4 hv;
        hv.x = 0.5f * a0 * (1.0f + erff(a0 * 0.70710678118f));
        hv.y = 0.5f * a1 * (1.0f + erff(a1 * 0.70710678118f));
        hv.z = 0.5f * a2 * (1.0f + erff(a2 * 0.70710678118f));
        hv.w = 0.5f * a3 * (1.0f + erff(a3 * 0.70710678118f));
        *(float4*)&hs[r * FFDIM + 4 * g + 128 * c4] = hv;      // conflict-free
    }
    __syncthreads();

    // ---- FFN GEMM2: y2 = (hs @ W2)[row, 4g..4g+3] ----
    float4 y2 = make_float4(0.f, 0.f, 0.f, 0.f);
    for (int j0 = 0; j0 < FFDIM; j0 += 4) {
        float4 hv = *(const float4*)&hs[r * FFDIM + j0];       // LDS broadcast
        #pragma unroll
        for (int u = 0; u < 4; ++u) {
            float4 w = *(const float4*)&W2[(size_t)(j0 + u) * HH + 4 * g];
            float hu = ((const float*)&hv)[u];
            y2.x += hu * w.x;  y2.y += hu * w.y;
            y2.z += hu * w.z;  y2.w += hu * w.w;
        }
    }
    {
        float4 bv = *(const float4*)&b2[4 * g];
        y2.x += bv.x + x1v.x;  y2.y += bv.y + x1v.y;           // residual
        y2.z += bv.z + x1v.z;  y2.w += bv.w + x1v.w;
    }

    // ---- LN2 ----
    s  = y2.x + y2.y + y2.z + y2.w;
    s2 = y2.x * y2.x + y2.y * y2.y + y2.z * y2.z + y2.w * y2.w;
    #pragma unroll
    for (int mask = 16; mask > 0; mask >>= 1) {
        s  += __shfl_xor(s,  mask);
        s2 += __shfl_xor(s2, mask);
    }
    mean = s * (1.0f / HH);
    var  = s2 * (1.0f / HH) - mean * mean;
    rstd = rsqrtf(var + 1e-5f);
    {
        float4 gg = *(const float4*)&l2g[4 * g];
        float4 bb = *(const float4*)&l2b[4 * g];
        float4 o;
        o.x = (y2.x - mean) * rstd * gg.x + bb.x;
        o.y = (y2.y - mean) * rstd * gg.y + bb.y;
        o.z = (y2.z - mean) * rstd * gg.z + bb.z;
        o.w = (y2.w - mean) * rstd * gg.w + bb.w;
        *(float4*)&out[(size_t)row * HH + 4 * g] = o;          // coalesced
    }
}

// ---------------------------------------------------------------------------
extern "C" void kernel_launch(void* const* d_in, const int* in_sizes, int n_in,
                              void* d_out, int out_size, void* d_ws, size_t ws_size,
                              hipStream_t stream)
{
    const float* x   = (const float*)d_in[0];
    const int*   ei  = (const int*)d_in[1];
    const float* ea  = (const float*)d_in[2];
    const float* Wq  = (const float*)d_in[3];
    const float* bq  = (const float*)d_in[4];
    const float* Wk  = (const float*)d_in[5];
    const float* bk  = (const float*)d_in[6];
    const float* Wv  = (const float*)d_in[7];
    const float* bv  = (const float*)d_in[8];
    const float* We  = (const float*)d_in[9];
    const float* be  = (const float*)d_in[10];
    const float* Wo  = (const float*)d_in[11];
    const float* bo  = (const float*)d_in[12];
    const float* l1g = (const float*)d_in[13];
    const float* l1b = (const float*)d_in[14];
    const float* W1  = (const float*)d_in[15];
    const float* b1  = (const float*)d_in[16];
    const float* W2  = (const float*)d_in[17];
    const float* b2  = (const float*)d_in[18];
    const float* l2g = (const float*)d_in[19];
    const float* l2b = (const float*)d_in[20];
    float* out = (float*)d_out;

    const int n = in_sizes[0] / HH;       // 10000
    const int E = in_sizes[1] / 2;        // 320000

    float* ws      = (float*)d_ws;
    float* q       = ws;
    float* k       = q       + (size_t)n * HH;
    float* v       = k       + (size_t)n * HH;
    float* csr_eb  = v       + (size_t)n * HH;            // E*8 floats
    float* agg     = csr_eb  + (size_t)E * NHEAD;         // n*128 floats
    int*   cnt     = (int*)(agg + (size_t)n * HH);        // n ints
    int*   cursor  = cnt     + n;                         // n ints
    int*   rowptr  = cursor  + n;                         // n+1 ints
    int*   csr_src = rowptr  + (n + 1);                   // E ints

    qkv_kernel<<<n / BM, 512, 0, stream>>>(x, Wq, bq, Wk, bk, Wv, bv,
                                           q, k, v, cnt, cursor);
    hist_kernel<<<(E + 255) / 256, 256, 0, stream>>>(ei, E, cnt);
    scan_kernel<<<1, SCAN_T, 0, stream>>>(cnt, n, rowptr);
    scatter_kernel<<<(E + 255) / 256, 256, 0, stream>>>(ei, E, ea, We, be,
                                                        rowptr, cursor,
                                                        csr_src, csr_eb);
    edge_kernel<<<n, 128, 0, stream>>>(q, k, v, rowptr, csr_src, csr_eb, agg);
    tail_kernel<<<n / BM, 512, 0, stream>>>(x, agg, Wo, bo, l1g, l1b,
                                            W1, b1, W2, b2, l2g, l2b, out);
}

// Round 12
// 315.904 us; speedup vs baseline: 1.3811x; 1.3811x over previous
//
#include <hip/hip_runtime.h>
#include <hip/hip_bf16.h>

#define HH    128
#define NHEAD 8
#define HDIM  16
#define EDIM  32
#define FFDIM 512
#define BM    16     // node rows per block (qkv + tail)
#define CHUNK 16     // edges per chunk in edge_kernel

// ---------------------------------------------------------------------------
// K1: q,k,v projections, tiled: BM=16 rows/block, 512 threads.
// Also zeroes cnt/cursor for the CSR build (ws is poisoned each call).
// ---------------------------------------------------------------------------
__global__ __launch_bounds__(512)
void qkv_kernel(const float* __restrict__ x,
                const float* __restrict__ Wq, const float* __restrict__ bq,
                const float* __restrict__ Wk, const float* __restrict__ bk,
                const float* __restrict__ Wv, const float* __restrict__ bv,
                float* __restrict__ q, float* __restrict__ k, float* __restrict__ v,
                int* __restrict__ cnt, int* __restrict__ cursor)
{
    const int row0 = blockIdx.x * BM;
    const int t  = threadIdx.x;
    const int rg = t >> 7;
    const int c  = t & 127;
    __shared__ float xs[BM * HH];

    if (t < BM)                cnt[row0 + t] = 0;
    else if (t < 2 * BM)       cursor[row0 + (t - BM)] = 0;
    // stage x tile (16 rows x 128) — 4 floats per thread, coalesced
    *(float4*)&xs[t * 4] = *(const float4*)&x[(size_t)row0 * HH + t * 4];
    __syncthreads();

    float aq[4] = {0.f, 0.f, 0.f, 0.f};
    float ak[4] = {0.f, 0.f, 0.f, 0.f};
    float av[4] = {0.f, 0.f, 0.f, 0.f};
    for (int i0 = 0; i0 < HH; i0 += 4) {
        float4 xr[4];
        #pragma unroll
        for (int r = 0; r < 4; ++r)
            xr[r] = *(const float4*)&xs[(4 * rg + r) * HH + i0];   // wave-broadcast
        #pragma unroll
        for (int u = 0; u < 4; ++u) {
            float wq = Wq[(i0 + u) * HH + c];
            float wk = Wk[(i0 + u) * HH + c];
            float wv = Wv[(i0 + u) * HH + c];
            #pragma unroll
            for (int r = 0; r < 4; ++r) {
                float xv = ((const float*)&xr[r])[u];
                aq[r] += xv * wq;  ak[r] += xv * wk;  av[r] += xv * wv;
            }
        }
    }
    float bqv = bq[c], bkv = bk[c], bvv = bv[c];
    #pragma unroll
    for (int r = 0; r < 4; ++r) {
        size_t o = (size_t)(row0 + 4 * rg + r) * HH + c;
        q[o] = aq[r] + bqv;
        k[o] = ak[r] + bkv;
        v[o] = av[r] + bvv;
    }
}

// ---------------------------------------------------------------------------
// K2: degree histogram over dst
// ---------------------------------------------------------------------------
__global__ void hist_kernel(const int* __restrict__ ei, int E, int* __restrict__ cnt)
{
    int e = blockIdx.x * 256 + threadIdx.x;
    if (e < E) atomicAdd(&cnt[ei[E + e]], 1);
}

// ---------------------------------------------------------------------------
// K3: exclusive prefix sum of cnt[0..n) -> rowptr[0..n]  (single block)
// ---------------------------------------------------------------------------
#define SCAN_T 1024
__global__ __launch_bounds__(SCAN_T)
void scan_kernel(const int* __restrict__ cnt, int n, int* __restrict__ rowptr)
{
    __shared__ int part[SCAN_T];
    const int t = threadIdx.x;
    const int per = (n + SCAN_T - 1) / SCAN_T;
    const int beg = t * per;
    const int end = min(beg + per, n);
    int sum = 0;
    for (int i = beg; i < end; ++i) sum += cnt[i];
    part[t] = sum;
    __syncthreads();
    // Hillis-Steele inclusive scan
    for (int off = 1; off < SCAN_T; off <<= 1) {
        int vv = (t >= off) ? part[t - off] : 0;
        __syncthreads();
        part[t] += vv;
        __syncthreads();
    }
    int base = (t == 0) ? 0 : part[t - 1];
    for (int i = beg; i < end; ++i) { rowptr[i] = base; base += cnt[i]; }
    if (t == SCAN_T - 1) rowptr[n] = base;
}

// ---------------------------------------------------------------------------
// K4: scatter edges into CSR slots; compute edge bias (ea@We+be) into
//     csr_eb (CSR-ordered so the edge kernel reads it contiguously).
// ---------------------------------------------------------------------------
__global__ __launch_bounds__(256)
void scatter_kernel(const int* __restrict__ ei, int E,
                    const float* __restrict__ ea,
                    const float* __restrict__ We, const float* __restrict__ be,
                    const int* __restrict__ rowptr, int* __restrict__ cursor,
                    int* __restrict__ csr_src, float* __restrict__ csr_eb)
{
    __shared__ float wsh[EDIM * NHEAD];
    __shared__ float bsh[NHEAD];
    const int t = threadIdx.x;
    if (t < EDIM * NHEAD) wsh[t] = We[t];
    if (t < NHEAD) bsh[t] = be[t];
    __syncthreads();
    int e = blockIdx.x * 256 + t;
    if (e >= E) return;
    int src = ei[e], dst = ei[E + e];
    int slot = rowptr[dst] + atomicAdd(&cursor[dst], 1);
    csr_src[slot] = src;
    float eb[NHEAD];
    #pragma unroll
    for (int h = 0; h < NHEAD; ++h) eb[h] = bsh[h];
    const float* eap = ea + (size_t)e * EDIM;
    #pragma unroll
    for (int j0 = 0; j0 < EDIM; j0 += 4) {
        float4 a = *(const float4*)&eap[j0];
        #pragma unroll
        for (int h = 0; h < NHEAD; ++h) {
            eb[h] += a.x * wsh[(j0    ) * NHEAD + h]
                   + a.y * wsh[(j0 + 1) * NHEAD + h]
                   + a.z * wsh[(j0 + 2) * NHEAD + h]
                   + a.w * wsh[(j0 + 3) * NHEAD + h];
        }
    }
    #pragma unroll
    for (int h = 0; h < NHEAD; ++h) csr_eb[(size_t)slot * NHEAD + h] = eb[h];
}

// ---------------------------------------------------------------------------
// K5: fused edge phase — per dst node: scores + online softmax + weighted
// aggregation. One block of 128 threads per node. No atomics.
// ---------------------------------------------------------------------------
__global__ __launch_bounds__(128)
void edge_kernel(const float* __restrict__ q, const float* __restrict__ k,
                 const float* __restrict__ v,
                 const int* __restrict__ rowptr,
                 const int* __restrict__ csr_src, const float* __restrict__ csr_eb,
                 float* __restrict__ agg)
{
    const int node = blockIdx.x;
    const int t = threadIdx.x;
    const int c = t >> 3, h = t & 7;
    const int f = t, fh = t >> 4;
    __shared__ float ks[HH];
    __shared__ float sraw[CHUNK][NHEAD];
    __shared__ float p[CHUNK][NHEAD];
    __shared__ int   ssrc[CHUNK];
    __shared__ float m[NHEAD], dn[NHEAD], fac[NHEAD];

    ks[t] = k[(size_t)node * HH + t];
    if (t < NHEAD) { m[t] = -3.0e38f; dn[t] = 0.f; }
    const int beg = rowptr[node], end = rowptr[node + 1];
    float acc = 0.f;
    __syncthreads();

    for (int b0 = beg; b0 < end; b0 += CHUNK) {
        const int C = min(CHUNK, end - b0);
        float sc = -3.0e38f;
        if (c < C) {
            int src = csr_src[b0 + c];          // 8 lanes same addr -> broadcast
            if (h == 0) ssrc[c] = src;
            const float* qp = q + (size_t)src * HH + h * HDIM;
            float d0 = 0.f;
            #pragma unroll
            for (int d = 0; d < HDIM; d += 4) {
                float4 qv = *(const float4*)&qp[d];
                d0 += qv.x * ks[h * HDIM + d]     + qv.y * ks[h * HDIM + d + 1]
                    + qv.z * ks[h * HDIM + d + 2] + qv.w * ks[h * HDIM + d + 3];
            }
            sc = d0 * 0.25f + csr_eb[(size_t)(b0 + c) * NHEAD + h];  // contiguous
        }
        sraw[c][h] = sc;
        __syncthreads();
        if (t < NHEAD) {
            float mo = m[t], mc = -3.0e38f;
            #pragma unroll 4
            for (int cc = 0; cc < CHUNK; ++cc) mc = fmaxf(mc, sraw[cc][t]);
            float mn = fmaxf(mo, mc);
            float fa = __expf(mo - mn);
            float s = 0.f;
            #pragma unroll 4
            for (int cc = 0; cc < CHUNK; ++cc) {
                float pe = __expf(sraw[cc][t] - mn);
                p[cc][t] = pe;  s += pe;
            }
            dn[t] = dn[t] * fa + s;
            m[t] = mn;  fac[t] = fa;
        }
        __syncthreads();
        acc *= fac[fh];
        for (int cc = 0; cc < C; ++cc)
            acc += p[cc][fh] * v[(size_t)ssrc[cc] * HH + f];   // 512B coalesced
        __syncthreads();   // protect LDS for next chunk
    }
    agg[(size_t)node * HH + f] = acc / (dn[fh] + 1e-8f);
}

// ---------------------------------------------------------------------------
// K6 (fused tail): out0 = agg@Wo+bo; x1 = LN1(x+out0);
//                  h = gelu(x1@W1+b1); out = LN2(x1 + h@W2+b2)
// BM=16 rows, 256 threads: rg=t>>7 (2 groups of 8 rows), c=t&127 (1 col).
// Weight redundancy R=2 per block (vs 4 in r9, 16 in r10) -> ~0.72 GB total
// L2 weight traffic. Weight loads scalar (coalesced 256B/wave); each load
// amortized over 8 row-FMAs. LDS row reads are wave-uniform broadcasts.
// ---------------------------------------------------------------------------
__global__ __launch_bounds__(256)
void tail_kernel(const float* __restrict__ x, const float* __restrict__ agg,
                 const float* __restrict__ Wo, const float* __restrict__ bo,
                 const float* __restrict__ l1g, const float* __restrict__ l1b,
                 const float* __restrict__ W1, const float* __restrict__ b1,
                 const float* __restrict__ W2, const float* __restrict__ b2,
                 const float* __restrict__ l2g, const float* __restrict__ l2b,
                 float* __restrict__ out)
{
    const int row0 = blockIdx.x * BM;
    const int t  = threadIdx.x;
    const int rg = t >> 7;              // 0..1 -> rows 8rg..8rg+7
    const int c  = t & 127;
    const int wh = (t >> 6) & 1;        // wave-half within row-group
    const int rbase = 8 * rg;

    __shared__ float xs[BM * HH];       // agg tile, then x1 tile (8KB)
    __shared__ float hs[BM * FFDIM];    // gelu(h) tile (32KB)
    __shared__ float redS[4][8], redS2[4][8];

    // stage agg tile: 2048 floats, 8 per thread, coalesced
    *(float4*)&xs[t * 8]     = *(const float4*)&agg[(size_t)row0 * HH + t * 8];
    *(float4*)&xs[t * 8 + 4] = *(const float4*)&agg[(size_t)row0 * HH + t * 8 + 4];
    __syncthreads();

    // ---- oproj: y[r] = (agg @ Wo)[rbase+r, c] ----
    float y[8] = {0.f, 0.f, 0.f, 0.f, 0.f, 0.f, 0.f, 0.f};
    for (int i0 = 0; i0 < HH; i0 += 4) {
        float4 xr[8];
        #pragma unroll
        for (int r = 0; r < 8; ++r)
            xr[r] = *(const float4*)&xs[(rbase + r) * HH + i0];   // broadcast
        #pragma unroll
        for (int u = 0; u < 4; ++u) {
            float w = Wo[(size_t)(i0 + u) * HH + c];
            #pragma unroll
            for (int r = 0; r < 8; ++r) y[r] += ((const float*)&xr[r])[u] * w;
        }
    }
    {
        float bov = bo[c];
        #pragma unroll
        for (int r = 0; r < 8; ++r)
            y[r] += bov + x[(size_t)(row0 + rbase + r) * HH + c];   // residual
    }

    // ---- LN1 (sum + sumsq, 128-thread reduction per row) ----
    float s[8], s2[8];
    #pragma unroll
    for (int r = 0; r < 8; ++r) { s[r] = y[r]; s2[r] = y[r] * y[r]; }
    #pragma unroll
    for (int off = 32; off > 0; off >>= 1) {
        #pragma unroll
        for (int r = 0; r < 8; ++r) {
            s[r]  += __shfl_down(s[r],  off);
            s2[r] += __shfl_down(s2[r], off);
        }
    }
    if ((t & 63) == 0) {
        #pragma unroll
        for (int r = 0; r < 8; ++r) {
            redS [rg * 2 + wh][r] = s[r];
            redS2[rg * 2 + wh][r] = s2[r];
        }
    }
    __syncthreads();
    float x1v[8];
    {
        float g1 = l1g[c], bb1 = l1b[c];
        #pragma unroll
        for (int r = 0; r < 8; ++r) {
            float ssum = redS [rg * 2][r] + redS [rg * 2 + 1][r];
            float ssq  = redS2[rg * 2][r] + redS2[rg * 2 + 1][r];
            float mean = ssum * (1.0f / HH);
            float var  = ssq  * (1.0f / HH) - mean * mean;
            x1v[r] = (y[r] - mean) * rsqrtf(var + 1e-5f) * g1 + bb1;
        }
    }
    // overwrite xs with x1 (all agg reads done before the barrier above)
    #pragma unroll
    for (int r = 0; r < 8; ++r) xs[(rbase + r) * HH + c] = x1v[r];
    __syncthreads();

    // ---- FFN GEMM1: h[r][k] for FF cols c+128k ----
    float h[8][4];
    #pragma unroll
    for (int r = 0; r < 8; ++r)
        #pragma unroll
        for (int kk = 0; kk < 4; ++kk) h[r][kk] = 0.f;
    for (int i0 = 0; i0 < HH; i0 += 4) {
        float4 xr[8];
        #pragma unroll
        for (int r = 0; r < 8; ++r)
            xr[r] = *(const float4*)&xs[(rbase + r) * HH + i0];   // broadcast
        #pragma unroll
        for (int u = 0; u < 4; ++u) {
            const float* wrow = &W1[(size_t)(i0 + u) * FFDIM + c];
            float w0 = wrow[0], w1 = wrow[128], w2 = wrow[256], w3 = wrow[384];
            #pragma unroll
            for (int r = 0; r < 8; ++r) {
                float xu = ((const float*)&xr[r])[u];
                h[r][0] += xu * w0;  h[r][1] += xu * w1;
                h[r][2] += xu * w2;  h[r][3] += xu * w3;
            }
        }
    }
    {
        float b10 = b1[c], b11 = b1[c + 128], b12 = b1[c + 256], b13 = b1[c + 384];
        #pragma unroll
        for (int r = 0; r < 8; ++r) {
            float a0 = h[r][0] + b10, a1 = h[r][1] + b11;
            float a2 = h[r][2] + b12, a3 = h[r][3] + b13;
            float* hrow = &hs[(rbase + r) * FFDIM + c];
            hrow[0]   = 0.5f * a0 * (1.0f + erff(a0 * 0.70710678118f));
            hrow[128] = 0.5f * a1 * (1.0f + erff(a1 * 0.70710678118f));
            hrow[256] = 0.5f * a2 * (1.0f + erff(a2 * 0.70710678118f));
            hrow[384] = 0.5f * a3 * (1.0f + erff(a3 * 0.70710678118f));
        }
    }
    __syncthreads();

    // ---- FFN GEMM2: y2[r] = (hs @ W2)[rbase+r, c] ----
    float y2[8] = {0.f, 0.f, 0.f, 0.f, 0.f, 0.f, 0.f, 0.f};
    for (int j0 = 0; j0 < FFDIM; j0 += 4) {
        float4 hr[8];
        #pragma unroll
        for (int r = 0; r < 8; ++r)
            hr[r] = *(const float4*)&hs[(rbase + r) * FFDIM + j0];  // broadcast
        #pragma unroll
        for (int u = 0; u < 4; ++u) {
            float w = W2[(size_t)(j0 + u) * HH + c];
            #pragma unroll
            for (int r = 0; r < 8; ++r) y2[r] += ((const float*)&hr[r])[u] * w;
        }
    }
    {
        float b2v = b2[c];
        #pragma unroll
        for (int r = 0; r < 8; ++r) y2[r] += b2v + x1v[r];   // residual
    }

    // ---- LN2 ----
    #pragma unroll
    for (int r = 0; r < 8; ++r) { s[r] = y2[r]; s2[r] = y2[r] * y2[r]; }
    #pragma unroll
    for (int off = 32; off > 0; off >>= 1) {
        #pragma unroll
        for (int r = 0; r < 8; ++r) {
            s[r]  += __shfl_down(s[r],  off);
            s2[r] += __shfl_down(s2[r], off);
        }
    }
    if ((t & 63) == 0) {
        #pragma unroll
        for (int r = 0; r < 8; ++r) {
            redS [rg * 2 + wh][r] = s[r];
            redS2[rg * 2 + wh][r] = s2[r];
        }
    }
    __syncthreads();
    {
        float g2 = l2g[c], bb2 = l2b[c];
        #pragma unroll
        for (int r = 0; r < 8; ++r) {
            float ssum = redS [rg * 2][r] + redS [rg * 2 + 1][r];
            float ssq  = redS2[rg * 2][r] + redS2[rg * 2 + 1][r];
            float mean = ssum * (1.0f / HH);
            float var  = ssq  * (1.0f / HH) - mean * mean;
            out[(size_t)(row0 + rbase + r) * HH + c] =
                (y2[r] - mean) * rsqrtf(var + 1e-5f) * g2 + bb2;
        }
    }
}

// ---------------------------------------------------------------------------
extern "C" void kernel_launch(void* const* d_in, const int* in_sizes, int n_in,
                              void* d_out, int out_size, void* d_ws, size_t ws_size,
                              hipStream_t stream)
{
    const float* x   = (const float*)d_in[0];
    const int*   ei  = (const int*)d_in[1];
    const float* ea  = (const float*)d_in[2];
    const float* Wq  = (const float*)d_in[3];
    const float* bq  = (const float*)d_in[4];
    const float* Wk  = (const float*)d_in[5];
    const float* bk  = (const float*)d_in[6];
    const float* Wv  = (const float*)d_in[7];
    const float* bv  = (const float*)d_in[8];
    const float* We  = (const float*)d_in[9];
    const float* be  = (const float*)d_in[10];
    const float* Wo  = (const float*)d_in[11];
    const float* bo  = (const float*)d_in[12];
    const float* l1g = (const float*)d_in[13];
    const float* l1b = (const float*)d_in[14];
    const float* W1  = (const float*)d_in[15];
    const float* b1  = (const float*)d_in[16];
    const float* W2  = (const float*)d_in[17];
    const float* b2  = (const float*)d_in[18];
    const float* l2g = (const float*)d_in[19];
    const float* l2b = (const float*)d_in[20];
    float* out = (float*)d_out;

    const int n = in_sizes[0] / HH;       // 10000
    const int E = in_sizes[1] / 2;        // 320000

    float* ws      = (float*)d_ws;
    float* q       = ws;
    float* k       = q       + (size_t)n * HH;
    float* v       = k       + (size_t)n * HH;
    float* csr_eb  = v       + (size_t)n * HH;            // E*8 floats
    float* agg     = csr_eb  + (size_t)E * NHEAD;         // n*128 floats
    int*   cnt     = (int*)(agg + (size_t)n * HH);        // n ints
    int*   cursor  = cnt     + n;                         // n ints
    int*   rowptr  = cursor  + n;                         // n+1 ints
    int*   csr_src = rowptr  + (n + 1);                   // E ints

    qkv_kernel<<<n / BM, 512, 0, stream>>>(x, Wq, bq, Wk, bk, Wv, bv,
                                           q, k, v, cnt, cursor);
    hist_kernel<<<(E + 255) / 256, 256, 0, stream>>>(ei, E, cnt);
    scan_kernel<<<1, SCAN_T, 0, stream>>>(cnt, n, rowptr);
    scatter_kernel<<<(E + 255) / 256, 256, 0, stream>>>(ei, E, ea, We, be,
                                                        rowptr, cursor,
                                                        csr_src, csr_eb);
    edge_kernel<<<n, 128, 0, stream>>>(q, k, v, rowptr, csr_src, csr_eb, agg);
    tail_kernel<<<n / BM, 256, 0, stream>>>(x, agg, Wo, bo, l1g, l1b,
                                            W1, b1, W2, b2, l2g, l2b, out);
}